// Round 1
// baseline (8499.966 us; speedup 1.0000x reference)
//
#include <hip/hip_runtime.h>
#include <hip/hip_bf16.h>

#define D 128
#define EDGES_PER_BLOCK 32
#define EDGES_PER_WAVE 8

// ---------------- out = x ----------------
__global__ __launch_bounds__(256) void copy_kernel(float* __restrict__ out,
                                                   const float* __restrict__ x,
                                                   int n_elems) {
    int n4 = n_elems >> 2;
    const float4* src = (const float4*)x;
    float4* dst = (float4*)out;
    for (int i = blockIdx.x * blockDim.x + threadIdx.x; i < n4;
         i += gridDim.x * blockDim.x)
        dst[i] = src[i];
}

// ---------------- count types (LDS histogram) ----------------
__global__ __launch_bounds__(256) void count_types(const int* __restrict__ type,
                                                   int n, int* __restrict__ cnt) {
    __shared__ int h[4];
    if (threadIdx.x < 4) h[threadIdx.x] = 0;
    __syncthreads();
    for (int i = blockIdx.x * blockDim.x + threadIdx.x; i < n;
         i += gridDim.x * blockDim.x)
        atomicAdd(&h[type[i]], 1);
    __syncthreads();
    if (threadIdx.x < 4) atomicAdd(&cnt[threadIdx.x], h[threadIdx.x]);
}

// ---------------- padded exclusive scan (1 thread) ----------------
// meta layout (ints): [0..3]=cnt1, [4..7]=cnt2, [8..12]=pb1, [13..17]=pb2
__global__ void scan_pad(int* __restrict__ meta) {
    int p = 0;
    for (int t = 0; t < 4; t++) {
        meta[8 + t] = p;
        p += ((meta[t] + EDGES_PER_BLOCK - 1) / EDGES_PER_BLOCK) * EDGES_PER_BLOCK;
        meta[t] = 0;  // reset for scatter pass
    }
    meta[12] = p;
    p = 0;
    for (int t = 0; t < 4; t++) {
        meta[13 + t] = p;
        p += ((meta[4 + t] + EDGES_PER_BLOCK - 1) / EDGES_PER_BLOCK) * EDGES_PER_BLOCK;
        meta[4 + t] = 0;
    }
    meta[17] = p;
}

// ---------------- scatter edge ids into type buckets ----------------
__global__ __launch_bounds__(256) void scatter_type(const int* __restrict__ type,
                                                    int n,
                                                    const int* __restrict__ pb,
                                                    int* __restrict__ cnt,
                                                    int* __restrict__ sorted) {
    int lane = threadIdx.x & 63;
    for (int i = blockIdx.x * blockDim.x + threadIdx.x; i < n;
         i += gridDim.x * blockDim.x) {
        int t = type[i];
#pragma unroll
        for (int tt = 0; tt < 4; tt++) {
            if (t == tt) {
                unsigned long long m = __ballot(1);
                int leader = __ffsll((unsigned long long)m) - 1;
                int rank = __popcll(m & ((1ull << lane) - 1ull));
                int base = 0;
                if (lane == leader) base = atomicAdd(&cnt[tt], (int)__popcll(m));
                base = __shfl(base, leader);
                sorted[pb[tt] + base + rank] = i;
            }
        }
    }
}

// ---------------- arity-1 edge kernel ----------------
// Each block: 32 edges, all same type (sorted + padded). 4 waves x 8 edges.
// Lane owns output columns (lane) and (lane+64).
__global__ __launch_bounds__(256) void edge1_kernel(
    const float* __restrict__ x, const float* __restrict__ W1,
    const int* __restrict__ src, const int* __restrict__ tgt,
    const int* __restrict__ sorted, const int* __restrict__ meta,
    float* __restrict__ out) {
    __shared__ float xs[EDGES_PER_BLOCK][D];
    __shared__ int s_src[EDGES_PER_BLOCK];
    __shared__ int s_tgt[EDGES_PER_BLOCK];

    int tid = threadIdx.x;
    int g0 = blockIdx.x * EDGES_PER_BLOCK;
    const int* pb = meta + 8;
    int t = 0;
#pragma unroll
    for (int k = 1; k < 4; k++)
        if (g0 >= pb[k]) t = k;
    const float* __restrict__ W = W1 + (size_t)t * D * D;

    if (tid < EDGES_PER_BLOCK) {
        int eid = sorted[g0 + tid];
        int sv = -1, tv = -1;
        if (eid >= 0) { sv = src[eid]; tv = tgt[eid]; }
        s_src[tid] = sv;
        s_tgt[tid] = tv;
    }
    __syncthreads();

    // cooperative gather: 8 threads per row, fully coalesced float4
    {
        int r = tid >> 3;
        int sv = s_src[r];
        if (sv >= 0) {
            const float4* srow = (const float4*)(x + (size_t)sv * D);
            float4* drow = (float4*)(&xs[r][0]);
#pragma unroll
            for (int k = 0; k < 4; k++) {
                int f = (tid & 7) + 8 * k;
                drow[f] = srow[f];
            }
        }
    }
    __syncthreads();

    int wave = tid >> 6, lane = tid & 63;
    int e0 = wave * EDGES_PER_WAVE;
    float acc0[EDGES_PER_WAVE], acc1[EDGES_PER_WAVE];
#pragma unroll
    for (int e = 0; e < EDGES_PER_WAVE; e++) { acc0[e] = 0.f; acc1[e] = 0.f; }

    for (int i4 = 0; i4 < D / 4; i4++) {
        float4 xv[EDGES_PER_WAVE];
#pragma unroll
        for (int e = 0; e < EDGES_PER_WAVE; e++)
            xv[e] = ((const float4*)(&xs[e0 + e][0]))[i4];
#pragma unroll
        for (int s = 0; s < 4; s++) {
            int i = 4 * i4 + s;
            float w0 = W[i * D + lane];
            float w1 = W[i * D + 64 + lane];
            float xe;
#pragma unroll
            for (int e = 0; e < EDGES_PER_WAVE; e++) {
                xe = (s == 0) ? xv[e].x : (s == 1) ? xv[e].y : (s == 2) ? xv[e].z : xv[e].w;
                acc0[e] = fmaf(xe, w0, acc0[e]);
                acc1[e] = fmaf(xe, w1, acc1[e]);
            }
        }
    }

#pragma unroll
    for (int e = 0; e < EDGES_PER_WAVE; e++) {
        int tv = s_tgt[e0 + e];
        if (tv >= 0) {
            atomicAdd(&out[(size_t)tv * D + lane], acc0[e]);
            atomicAdd(&out[(size_t)tv * D + 64 + lane], acc1[e]);
        }
    }
}

// ---------------- arity-2 edge kernel (concat of 2 src rows, 256 -> 128) ----------------
__global__ __launch_bounds__(256) void edge2_kernel(
    const float* __restrict__ x, const float* __restrict__ W2,
    const int* __restrict__ src2, const int* __restrict__ tgt,
    const int* __restrict__ sorted, const int* __restrict__ meta,
    float* __restrict__ out) {
    __shared__ float xs[EDGES_PER_BLOCK][2 * D];
    __shared__ int s_srcA[EDGES_PER_BLOCK];
    __shared__ int s_srcB[EDGES_PER_BLOCK];
    __shared__ int s_tgt[EDGES_PER_BLOCK];

    int tid = threadIdx.x;
    int g0 = blockIdx.x * EDGES_PER_BLOCK;
    const int* pb = meta + 13;
    int t = 0;
#pragma unroll
    for (int k = 1; k < 4; k++)
        if (g0 >= pb[k]) t = k;
    const float* __restrict__ W = W2 + (size_t)t * 2 * D * D;

    if (tid < EDGES_PER_BLOCK) {
        int eid = sorted[g0 + tid];
        int sa = -1, sb = -1, tv = -1;
        if (eid >= 0) {
            sa = src2[2 * eid];
            sb = src2[2 * eid + 1];
            tv = tgt[eid];
        }
        s_srcA[tid] = sa; s_srcB[tid] = sb; s_tgt[tid] = tv;
    }
    __syncthreads();

    {
        int r = tid >> 3;
        int sa = s_srcA[r], sb = s_srcB[r];
        if (sa >= 0) {
            const float4* pa = (const float4*)(x + (size_t)sa * D);
            const float4* pbv = (const float4*)(x + (size_t)sb * D);
            float4* drow = (float4*)(&xs[r][0]);
#pragma unroll
            for (int k = 0; k < 8; k++) {
                int f = (tid & 7) + 8 * k;
                drow[f] = (k < 4) ? pa[f] : pbv[f - 32];
            }
        }
    }
    __syncthreads();

    int wave = tid >> 6, lane = tid & 63;
    int e0 = wave * EDGES_PER_WAVE;
    float acc0[EDGES_PER_WAVE], acc1[EDGES_PER_WAVE];
#pragma unroll
    for (int e = 0; e < EDGES_PER_WAVE; e++) { acc0[e] = 0.f; acc1[e] = 0.f; }

    for (int i4 = 0; i4 < 2 * D / 4; i4++) {
        float4 xv[EDGES_PER_WAVE];
#pragma unroll
        for (int e = 0; e < EDGES_PER_WAVE; e++)
            xv[e] = ((const float4*)(&xs[e0 + e][0]))[i4];
#pragma unroll
        for (int s = 0; s < 4; s++) {
            int i = 4 * i4 + s;
            float w0 = W[i * D + lane];
            float w1 = W[i * D + 64 + lane];
            float xe;
#pragma unroll
            for (int e = 0; e < EDGES_PER_WAVE; e++) {
                xe = (s == 0) ? xv[e].x : (s == 1) ? xv[e].y : (s == 2) ? xv[e].z : xv[e].w;
                acc0[e] = fmaf(xe, w0, acc0[e]);
                acc1[e] = fmaf(xe, w1, acc1[e]);
            }
        }
    }

#pragma unroll
    for (int e = 0; e < EDGES_PER_WAVE; e++) {
        int tv = s_tgt[e0 + e];
        if (tv >= 0) {
            atomicAdd(&out[(size_t)tv * D + lane], acc0[e]);
            atomicAdd(&out[(size_t)tv * D + 64 + lane], acc1[e]);
        }
    }
}

// ---------------- fallback (no workspace): one wave per edge ----------------
__global__ __launch_bounds__(256) void e1_simple(
    const float* __restrict__ x, const float* __restrict__ W1,
    const int* __restrict__ src, const int* __restrict__ tgt,
    const int* __restrict__ type, float* __restrict__ out, int n) {
    int lane = threadIdx.x & 63;
    int wid = (blockIdx.x * blockDim.x + threadIdx.x) >> 6;
    int nw = (gridDim.x * blockDim.x) >> 6;
    for (int e = wid; e < n; e += nw) {
        const float* W = W1 + (size_t)type[e] * D * D;
        const float* xr = x + (size_t)src[e] * D;
        float a0 = 0.f, a1 = 0.f;
        for (int i = 0; i < D; i++) {
            float xv = xr[i];
            a0 = fmaf(xv, W[i * D + lane], a0);
            a1 = fmaf(xv, W[i * D + 64 + lane], a1);
        }
        atomicAdd(&out[(size_t)tgt[e] * D + lane], a0);
        atomicAdd(&out[(size_t)tgt[e] * D + 64 + lane], a1);
    }
}

__global__ __launch_bounds__(256) void e2_simple(
    const float* __restrict__ x, const float* __restrict__ W2,
    const int* __restrict__ src2, const int* __restrict__ tgt,
    const int* __restrict__ type, float* __restrict__ out, int n) {
    int lane = threadIdx.x & 63;
    int wid = (blockIdx.x * blockDim.x + threadIdx.x) >> 6;
    int nw = (gridDim.x * blockDim.x) >> 6;
    for (int e = wid; e < n; e += nw) {
        const float* W = W2 + (size_t)type[e] * 2 * D * D;
        const float* xrA = x + (size_t)src2[2 * e] * D;
        const float* xrB = x + (size_t)src2[2 * e + 1] * D;
        float a0 = 0.f, a1 = 0.f;
        for (int i = 0; i < 2 * D; i++) {
            float xv = (i < D) ? xrA[i] : xrB[i - D];
            a0 = fmaf(xv, W[i * D + lane], a0);
            a1 = fmaf(xv, W[i * D + 64 + lane], a1);
        }
        atomicAdd(&out[(size_t)tgt[e] * D + lane], a0);
        atomicAdd(&out[(size_t)tgt[e] * D + 64 + lane], a1);
    }
}

extern "C" void kernel_launch(void* const* d_in, const int* in_sizes, int n_in,
                              void* d_out, int out_size, void* d_ws, size_t ws_size,
                              hipStream_t stream) {
    const float* x = (const float*)d_in[0];
    const float* W1 = (const float*)d_in[1];
    const float* W2 = (const float*)d_in[2];
    const int* src1 = (const int*)d_in[3];
    const int* tgt1 = (const int*)d_in[4];
    const int* type1 = (const int*)d_in[5];
    const int* src2 = (const int*)d_in[6];
    const int* tgt2 = (const int*)d_in[7];
    const int* type2 = (const int*)d_in[8];
    float* out = (float*)d_out;

    int n_nodes = in_sizes[0] / D;
    int E1c = in_sizes[3];
    int E2c = in_sizes[7];

    // out = x
    copy_kernel<<<2048, 256, 0, stream>>>(out, x, n_nodes * D);

    int grid1 = (E1c + 4 * (EDGES_PER_BLOCK - 1) + EDGES_PER_BLOCK - 1) / EDGES_PER_BLOCK;
    int grid2 = (E2c + 4 * (EDGES_PER_BLOCK - 1) + EDGES_PER_BLOCK - 1) / EDGES_PER_BLOCK;
    int cap1 = grid1 * EDGES_PER_BLOCK;
    int cap2 = grid2 * EDGES_PER_BLOCK;
    size_t need = 128 + (size_t)4 * (cap1 + cap2);

    if (ws_size >= need) {
        int* meta = (int*)d_ws;
        int* sorted1 = meta + 32;
        int* sorted2 = sorted1 + cap1;

        hipMemsetAsync(meta, 0, 128, stream);
        hipMemsetAsync(sorted1, 0xFF, (size_t)4 * (cap1 + cap2), stream);

        count_types<<<512, 256, 0, stream>>>(type1, E1c, meta + 0);
        count_types<<<512, 256, 0, stream>>>(type2, E2c, meta + 4);
        scan_pad<<<1, 1, 0, stream>>>(meta);
        scatter_type<<<512, 256, 0, stream>>>(type1, E1c, meta + 8, meta + 0, sorted1);
        scatter_type<<<512, 256, 0, stream>>>(type2, E2c, meta + 13, meta + 4, sorted2);

        edge1_kernel<<<grid1, 256, 0, stream>>>(x, W1, src1, tgt1, sorted1, meta, out);
        edge2_kernel<<<grid2, 256, 0, stream>>>(x, W2, src2, tgt2, sorted2, meta, out);
    } else {
        e1_simple<<<2048, 256, 0, stream>>>(x, W1, src1, tgt1, type1, out, E1c);
        e2_simple<<<2048, 256, 0, stream>>>(x, W2, src2, tgt2, type2, out, E2c);
    }
}

// Round 2
// 942.355 us; speedup vs baseline: 9.0199x; 9.0199x over previous
//
#include <hip/hip_runtime.h>
#include <hip/hip_bf16.h>

#define D 128
#define EPB 32  // edges per block

typedef __attribute__((ext_vector_type(8))) short bf16x8;
typedef __attribute__((ext_vector_type(4))) float f32x4;

__device__ inline unsigned short f2bf(float f) {
    union { float f; unsigned int u; } v;
    v.f = f;
    unsigned int u = v.u;
    unsigned int r = u + 0x7fffu + ((u >> 16) & 1u);  // RNE
    return (unsigned short)(r >> 16);
}

// ---------------- out = x ----------------
__global__ __launch_bounds__(256) void copy_kernel(float* __restrict__ out,
                                                   const float* __restrict__ x,
                                                   int n_elems) {
    int n4 = n_elems >> 2;
    const float4* src = (const float4*)x;
    float4* dst = (float4*)out;
    for (int i = blockIdx.x * blockDim.x + threadIdx.x; i < n4;
         i += gridDim.x * blockDim.x)
        dst[i] = src[i];
}

// ---------------- W[t][k][c] fp32 -> Wt[t][c][k] bf16 (tiled transpose) ----------------
__global__ __launch_bounds__(256) void conv_w(const float* __restrict__ W,
                                              unsigned short* __restrict__ Wt,
                                              int K) {
    __shared__ float tile[32][33];
    int k0 = blockIdx.x * 32, c0 = blockIdx.y * 32, t = blockIdx.z;
    int tr = threadIdx.x >> 5, tc = threadIdx.x & 31;
#pragma unroll
    for (int m = 0; m < 4; m++)
        tile[m * 8 + tr][tc] = W[((size_t)t * K + k0 + m * 8 + tr) * D + c0 + tc];
    __syncthreads();
#pragma unroll
    for (int m = 0; m < 4; m++)
        Wt[((size_t)t * D + c0 + m * 8 + tr) * K + k0 + tc] = f2bf(tile[tc][m * 8 + tr]);
}

// ---------------- count types ----------------
__global__ __launch_bounds__(256) void count_types(const int* __restrict__ type,
                                                   int n, int* __restrict__ cnt) {
    __shared__ int h[4];
    if (threadIdx.x < 4) h[threadIdx.x] = 0;
    __syncthreads();
    for (int i = blockIdx.x * blockDim.x + threadIdx.x; i < n;
         i += gridDim.x * blockDim.x)
        atomicAdd(&h[type[i]], 1);
    __syncthreads();
    if (threadIdx.x < 4) atomicAdd(&cnt[threadIdx.x], h[threadIdx.x]);
}

// meta: [0..3]=cnt1, [4..7]=cnt2, [8..12]=pb1, [13..17]=pb2
__global__ void scan_pad(int* __restrict__ meta) {
    int p = 0;
    for (int t = 0; t < 4; t++) {
        meta[8 + t] = p;
        p += ((meta[t] + EPB - 1) / EPB) * EPB;
        meta[t] = 0;
    }
    meta[12] = p;
    p = 0;
    for (int t = 0; t < 4; t++) {
        meta[13 + t] = p;
        p += ((meta[4 + t] + EPB - 1) / EPB) * EPB;
        meta[4 + t] = 0;
    }
    meta[17] = p;
}

__global__ __launch_bounds__(256) void scatter_type(const int* __restrict__ type,
                                                    int n,
                                                    const int* __restrict__ pb,
                                                    int* __restrict__ cnt,
                                                    int* __restrict__ sorted) {
    int lane = threadIdx.x & 63;
    for (int i = blockIdx.x * blockDim.x + threadIdx.x; i < n;
         i += gridDim.x * blockDim.x) {
        int t = type[i];
#pragma unroll
        for (int tt = 0; tt < 4; tt++) {
            if (t == tt) {
                unsigned long long m = __ballot(1);
                int leader = __ffsll((unsigned long long)m) - 1;
                int rank = __popcll(m & ((1ull << lane) - 1ull));
                int base = 0;
                if (lane == leader) base = atomicAdd(&cnt[tt], (int)__popcll(m));
                base = __shfl(base, leader);
                sorted[pb[tt] + base + rank] = i;
            }
        }
    }
}

// ================= MFMA edge kernels =================
// Block = 32 edges (one type), 4 waves. Wave w computes out cols [32w, 32w+32).
// A (32 x K) staged bf16 in LDS with XOR swizzle; B frags read from Wt (L2).
// mfma_f32_16x16x32_bf16: A-frag lane l: row=l&15, k=8*(l>>4)+j (contig 16B)
// C/D: col=lane&15, row=(lane>>4)*4+reg  [guide m89]

__global__ __launch_bounds__(256) void edge1_mfma(
    const float* __restrict__ x, const unsigned short* __restrict__ Wt1,
    const int* __restrict__ src, const int* __restrict__ tgt,
    const int* __restrict__ sorted, const int* __restrict__ meta,
    float* __restrict__ out) {
    __shared__ uint4 As4[512];  // 32 rows x 256B (swizzled)
    __shared__ int s_tgt[EPB];
    __shared__ int s_src[EPB];
    char* As = (char*)As4;

    int tid = threadIdx.x;
    int g0 = blockIdx.x * EPB;
    const int* pb = meta + 8;
    int t = 0;
#pragma unroll
    for (int k = 1; k < 4; k++)
        if (g0 >= pb[k]) t = k;
    const unsigned short* __restrict__ W = Wt1 + (size_t)t * D * D;

    if (tid < EPB) {
        int eid = sorted[g0 + tid];
        int sv = -1, tv = -1;
        if (eid >= 0) { sv = src[eid]; tv = tgt[eid]; }
        s_src[tid] = sv;
        s_tgt[tid] = tv;
    }
    __syncthreads();

    // gather + cvt: 8 threads/row, each handles 4 float4 units (u = u0+8q)
    {
        int r = tid >> 3, u0 = tid & 7;
        int sv = s_src[r];
        const float4* srow = (const float4*)(x + (size_t)sv * D);
#pragma unroll
        for (int q = 0; q < 4; q++) {
            int u = u0 + 8 * q;  // float4 unit 0..31
            float4 v = make_float4(0.f, 0.f, 0.f, 0.f);
            if (sv >= 0) v = srow[u];
            uint2 p;
            p.x = (unsigned)f2bf(v.x) | ((unsigned)f2bf(v.y) << 16);
            p.y = (unsigned)f2bf(v.z) | ((unsigned)f2bf(v.w) << 16);
            int byte = ((((u >> 1) * 16) ^ ((r & 7) << 4)) + (u & 1) * 8);
            *(uint2*)(As + r * 256 + byte) = p;
        }
    }
    __syncthreads();

    int wave = tid >> 6, lane = tid & 63;
    int c0 = wave * 32;
    int lrow = lane & 15, lgrp = lane >> 4;

    // preload all B fragments (8 x 16B from L2)
    bf16x8 b[2][4];
#pragma unroll
    for (int fc = 0; fc < 2; fc++)
#pragma unroll
        for (int kk = 0; kk < 4; kk++)
            b[fc][kk] = *(const bf16x8*)(W + (size_t)(c0 + fc * 16 + lrow) * D +
                                         kk * 32 + lgrp * 8);

    f32x4 acc[2][2];
#pragma unroll
    for (int i = 0; i < 2; i++)
#pragma unroll
        for (int j = 0; j < 2; j++) acc[i][j] = (f32x4){0.f, 0.f, 0.f, 0.f};

#pragma unroll
    for (int kk = 0; kk < 4; kk++) {
        bf16x8 a0, a1;
        {
            int r = lrow;
            a0 = *(const bf16x8*)(As + r * 256 +
                                  ((kk * 64 + lgrp * 16) ^ ((r & 7) << 4)));
        }
        {
            int r = 16 + lrow;
            a1 = *(const bf16x8*)(As + r * 256 +
                                  ((kk * 64 + lgrp * 16) ^ ((r & 7) << 4)));
        }
        acc[0][0] = __builtin_amdgcn_mfma_f32_16x16x32_bf16(a0, b[0][kk], acc[0][0], 0, 0, 0);
        acc[1][0] = __builtin_amdgcn_mfma_f32_16x16x32_bf16(a1, b[0][kk], acc[1][0], 0, 0, 0);
        acc[0][1] = __builtin_amdgcn_mfma_f32_16x16x32_bf16(a0, b[1][kk], acc[0][1], 0, 0, 0);
        acc[1][1] = __builtin_amdgcn_mfma_f32_16x16x32_bf16(a1, b[1][kk], acc[1][1], 0, 0, 0);
    }

#pragma unroll
    for (int fr = 0; fr < 2; fr++)
#pragma unroll
        for (int reg = 0; reg < 4; reg++) {
            int erow = fr * 16 + lgrp * 4 + reg;
            int tv = s_tgt[erow];
            if (tv >= 0) {
#pragma unroll
                for (int fc = 0; fc < 2; fc++)
                    atomicAdd(&out[(size_t)tv * D + c0 + fc * 16 + lrow],
                              acc[fr][fc][reg]);
            }
        }
}

__global__ __launch_bounds__(256) void edge2_mfma(
    const float* __restrict__ x, const unsigned short* __restrict__ Wt2,
    const int* __restrict__ src2, const int* __restrict__ tgt,
    const int* __restrict__ sorted, const int* __restrict__ meta,
    float* __restrict__ out) {
    __shared__ uint4 As4[1024];  // 32 rows x 512B (swizzled)
    __shared__ int s_tgt[EPB];
    __shared__ int s_srcA[EPB];
    __shared__ int s_srcB[EPB];
    char* As = (char*)As4;

    int tid = threadIdx.x;
    int g0 = blockIdx.x * EPB;
    const int* pb = meta + 13;
    int t = 0;
#pragma unroll
    for (int k = 1; k < 4; k++)
        if (g0 >= pb[k]) t = k;
    const unsigned short* __restrict__ W = Wt2 + (size_t)t * D * 2 * D;

    if (tid < EPB) {
        int eid = sorted[g0 + tid];
        int sa = -1, sb = -1, tv = -1;
        if (eid >= 0) { sa = src2[2 * eid]; sb = src2[2 * eid + 1]; tv = tgt[eid]; }
        s_srcA[tid] = sa;
        s_srcB[tid] = sb;
        s_tgt[tid] = tv;
    }
    __syncthreads();

    {
        int r = tid >> 3, u0 = tid & 7;
        int sa = s_srcA[r], sb = s_srcB[r];
        const float4* rowA = (const float4*)(x + (size_t)sa * D);
        const float4* rowB = (const float4*)(x + (size_t)sb * D);
#pragma unroll
        for (int q = 0; q < 8; q++) {
            int u = u0 + 8 * q;  // float4 unit 0..63 over concat row
            float4 v = make_float4(0.f, 0.f, 0.f, 0.f);
            if (sa >= 0) v = (u < 32) ? rowA[u] : rowB[u - 32];
            uint2 p;
            p.x = (unsigned)f2bf(v.x) | ((unsigned)f2bf(v.y) << 16);
            p.y = (unsigned)f2bf(v.z) | ((unsigned)f2bf(v.w) << 16);
            int byte = ((((u >> 1) * 16) ^ ((r & 7) << 4)) + (u & 1) * 8);
            *(uint2*)(As + r * 512 + byte) = p;
        }
    }
    __syncthreads();

    int wave = tid >> 6, lane = tid & 63;
    int c0 = wave * 32;
    int lrow = lane & 15, lgrp = lane >> 4;

    f32x4 acc[2][2];
#pragma unroll
    for (int i = 0; i < 2; i++)
#pragma unroll
        for (int j = 0; j < 2; j++) acc[i][j] = (f32x4){0.f, 0.f, 0.f, 0.f};

#pragma unroll
    for (int kk = 0; kk < 8; kk++) {
        bf16x8 b0 = *(const bf16x8*)(W + (size_t)(c0 + lrow) * 2 * D + kk * 32 + lgrp * 8);
        bf16x8 b1 = *(const bf16x8*)(W + (size_t)(c0 + 16 + lrow) * 2 * D + kk * 32 + lgrp * 8);
        bf16x8 a0, a1;
        {
            int r = lrow;
            a0 = *(const bf16x8*)(As + r * 512 +
                                  ((kk * 64 + lgrp * 16) ^ ((r & 7) << 4)));
        }
        {
            int r = 16 + lrow;
            a1 = *(const bf16x8*)(As + r * 512 +
                                  ((kk * 64 + lgrp * 16) ^ ((r & 7) << 4)));
        }
        acc[0][0] = __builtin_amdgcn_mfma_f32_16x16x32_bf16(a0, b0, acc[0][0], 0, 0, 0);
        acc[1][0] = __builtin_amdgcn_mfma_f32_16x16x32_bf16(a1, b0, acc[1][0], 0, 0, 0);
        acc[0][1] = __builtin_amdgcn_mfma_f32_16x16x32_bf16(a0, b1, acc[0][1], 0, 0, 0);
        acc[1][1] = __builtin_amdgcn_mfma_f32_16x16x32_bf16(a1, b1, acc[1][1], 0, 0, 0);
    }

#pragma unroll
    for (int fr = 0; fr < 2; fr++)
#pragma unroll
        for (int reg = 0; reg < 4; reg++) {
            int erow = fr * 16 + lgrp * 4 + reg;
            int tv = s_tgt[erow];
            if (tv >= 0) {
#pragma unroll
                for (int fc = 0; fc < 2; fc++)
                    atomicAdd(&out[(size_t)tv * D + c0 + fc * 16 + lrow],
                              acc[fr][fc][reg]);
            }
        }
}

// ---------------- fallback (no workspace): one wave per edge, fp32 ----------------
__global__ __launch_bounds__(256) void e1_simple(
    const float* __restrict__ x, const float* __restrict__ W1,
    const int* __restrict__ src, const int* __restrict__ tgt,
    const int* __restrict__ type, float* __restrict__ out, int n) {
    int lane = threadIdx.x & 63;
    int wid = (blockIdx.x * blockDim.x + threadIdx.x) >> 6;
    int nw = (gridDim.x * blockDim.x) >> 6;
    for (int e = wid; e < n; e += nw) {
        const float* W = W1 + (size_t)type[e] * D * D;
        const float* xr = x + (size_t)src[e] * D;
        float a0 = 0.f, a1 = 0.f;
        for (int i = 0; i < D; i++) {
            float xv = xr[i];
            a0 = fmaf(xv, W[i * D + lane], a0);
            a1 = fmaf(xv, W[i * D + 64 + lane], a1);
        }
        atomicAdd(&out[(size_t)tgt[e] * D + lane], a0);
        atomicAdd(&out[(size_t)tgt[e] * D + 64 + lane], a1);
    }
}

__global__ __launch_bounds__(256) void e2_simple(
    const float* __restrict__ x, const float* __restrict__ W2,
    const int* __restrict__ src2, const int* __restrict__ tgt,
    const int* __restrict__ type, float* __restrict__ out, int n) {
    int lane = threadIdx.x & 63;
    int wid = (blockIdx.x * blockDim.x + threadIdx.x) >> 6;
    int nw = (gridDim.x * blockDim.x) >> 6;
    for (int e = wid; e < n; e += nw) {
        const float* W = W2 + (size_t)type[e] * 2 * D * D;
        const float* xrA = x + (size_t)src2[2 * e] * D;
        const float* xrB = x + (size_t)src2[2 * e + 1] * D;
        float a0 = 0.f, a1 = 0.f;
        for (int i = 0; i < 2 * D; i++) {
            float xv = (i < D) ? xrA[i] : xrB[i - D];
            a0 = fmaf(xv, W[i * D + lane], a0);
            a1 = fmaf(xv, W[i * D + 64 + lane], a1);
        }
        atomicAdd(&out[(size_t)tgt[e] * D + lane], a0);
        atomicAdd(&out[(size_t)tgt[e] * D + 64 + lane], a1);
    }
}

extern "C" void kernel_launch(void* const* d_in, const int* in_sizes, int n_in,
                              void* d_out, int out_size, void* d_ws, size_t ws_size,
                              hipStream_t stream) {
    const float* x = (const float*)d_in[0];
    const float* W1 = (const float*)d_in[1];
    const float* W2 = (const float*)d_in[2];
    const int* src1 = (const int*)d_in[3];
    const int* tgt1 = (const int*)d_in[4];
    const int* type1 = (const int*)d_in[5];
    const int* src2 = (const int*)d_in[6];
    const int* tgt2 = (const int*)d_in[7];
    const int* type2 = (const int*)d_in[8];
    float* out = (float*)d_out;

    int n_nodes = in_sizes[0] / D;
    int E1c = in_sizes[3];
    int E2c = in_sizes[7];

    copy_kernel<<<2048, 256, 0, stream>>>(out, x, n_nodes * D);

    int grid1 = (E1c + 4 * (EPB - 1) + EPB - 1) / EPB;
    int grid2 = (E2c + 4 * (EPB - 1) + EPB - 1) / EPB;
    int cap1 = grid1 * EPB;
    int cap2 = grid2 * EPB;

    size_t base = (size_t)128 + (size_t)4 * (cap1 + cap2);
    base = (base + 255) & ~(size_t)255;
    size_t w1_elems = (size_t)4 * D * D;       // 65536
    size_t w2_elems = (size_t)4 * D * 2 * D;   // 131072
    size_t need = base + (w1_elems + w2_elems) * 2;

    if (ws_size >= need) {
        int* meta = (int*)d_ws;
        int* sorted1 = meta + 32;
        int* sorted2 = sorted1 + cap1;
        unsigned short* wt1 = (unsigned short*)((char*)d_ws + base);
        unsigned short* wt2 = wt1 + w1_elems;

        hipMemsetAsync(meta, 0, 128, stream);
        hipMemsetAsync(sorted1, 0xFF, (size_t)4 * (cap1 + cap2), stream);

        conv_w<<<dim3(4, 4, 4), 256, 0, stream>>>(W1, wt1, D);
        conv_w<<<dim3(8, 4, 4), 256, 0, stream>>>(W2, wt2, 2 * D);

        count_types<<<512, 256, 0, stream>>>(type1, E1c, meta + 0);
        count_types<<<512, 256, 0, stream>>>(type2, E2c, meta + 4);
        scan_pad<<<1, 1, 0, stream>>>(meta);
        scatter_type<<<512, 256, 0, stream>>>(type1, E1c, meta + 8, meta + 0, sorted1);
        scatter_type<<<512, 256, 0, stream>>>(type2, E2c, meta + 13, meta + 4, sorted2);

        edge1_mfma<<<grid1, 256, 0, stream>>>(x, wt1, src1, tgt1, sorted1, meta, out);
        edge2_mfma<<<grid2, 256, 0, stream>>>(x, wt2, src2, tgt2, sorted2, meta, out);
    } else {
        e1_simple<<<2048, 256, 0, stream>>>(x, W1, src1, tgt1, type1, out, E1c);
        e2_simple<<<2048, 256, 0, stream>>>(x, W2, src2, tgt2, type2, out, E2c);
    }
}

// Round 3
// 401.034 us; speedup vs baseline: 21.1951x; 2.3498x over previous
//
#include <hip/hip_runtime.h>
#include <hip/hip_bf16.h>

#define D 128
#define EPB 32   // edges per block (MFMA kernels)
#define NB 256   // blocks for hist/write passes

typedef __attribute__((ext_vector_type(8))) short bf16x8;
typedef __attribute__((ext_vector_type(4))) float f32x4;

__device__ inline unsigned short f2bf(float f) {
    union { float f; unsigned int u; } v;
    v.f = f;
    unsigned int u = v.u;
    unsigned int r = u + 0x7fffu + ((u >> 16) & 1u);  // RNE
    return (unsigned short)(r >> 16);
}

// ---------------- out = x ----------------
__global__ __launch_bounds__(256) void copy_kernel(float* __restrict__ out,
                                                   const float* __restrict__ x,
                                                   int n_elems) {
    int n4 = n_elems >> 2;
    const float4* src = (const float4*)x;
    float4* dst = (float4*)out;
    for (int i = blockIdx.x * blockDim.x + threadIdx.x; i < n4;
         i += gridDim.x * blockDim.x)
        dst[i] = src[i];
}

// ---------------- W[t][k][c] fp32 -> Wt[t][c][k] bf16 (tiled transpose) ----------------
__global__ __launch_bounds__(256) void conv_w(const float* __restrict__ W,
                                              unsigned short* __restrict__ Wt,
                                              int K) {
    __shared__ float tile[32][33];
    int k0 = blockIdx.x * 32, c0 = blockIdx.y * 32, t = blockIdx.z;
    int tr = threadIdx.x >> 5, tc = threadIdx.x & 31;
#pragma unroll
    for (int m = 0; m < 4; m++)
        tile[m * 8 + tr][tc] = W[((size_t)t * K + k0 + m * 8 + tr) * D + c0 + tc];
    __syncthreads();
#pragma unroll
    for (int m = 0; m < 4; m++)
        Wt[((size_t)t * D + c0 + m * 8 + tr) * K + k0 + tc] = f2bf(tile[tc][m * 8 + tr]);
}

// ---------------- pass 1: per-block type histogram (no global atomics) ----------------
__global__ __launch_bounds__(256) void hist_types(const int* __restrict__ type,
                                                  int n, int* __restrict__ hist) {
    __shared__ int h[4];
    if (threadIdx.x < 4) h[threadIdx.x] = 0;
    __syncthreads();
    for (int i = blockIdx.x * 256 + threadIdx.x; i < n; i += NB * 256)
        atomicAdd(&h[type[i]], 1);
    __syncthreads();
    if (threadIdx.x < 4) hist[blockIdx.x * 4 + threadIdx.x] = h[threadIdx.x];
}

// ---------------- pass 2: totals, padded bases, per-block offsets ----------------
// meta: [0..3]=total1, [4..7]=total2, [8..12]=pb1, [13..17]=pb2
__global__ void scan_offsets(int* __restrict__ meta,
                             const int* __restrict__ hist1, int* __restrict__ off1,
                             const int* __restrict__ hist2, int* __restrict__ off2) {
    int t = threadIdx.x;
    if (t < 4) {
        int s = 0;
        for (int b = 0; b < NB; b++) s += hist1[b * 4 + t];
        meta[t] = s;
    } else if (t < 8) {
        int tt = t - 4, s = 0;
        for (int b = 0; b < NB; b++) s += hist2[b * 4 + tt];
        meta[4 + tt] = s;
    }
    __syncthreads();
    if (t == 0) {
        int p = 0;
        for (int k = 0; k < 4; k++) {
            meta[8 + k] = p;
            p += ((meta[k] + EPB - 1) / EPB) * EPB;
        }
        meta[12] = p;
        p = 0;
        for (int k = 0; k < 4; k++) {
            meta[13 + k] = p;
            p += ((meta[4 + k] + EPB - 1) / EPB) * EPB;
        }
        meta[17] = p;
    }
    __syncthreads();
    if (t < 4) {
        int p = meta[8 + t];
        for (int b = 0; b < NB; b++) { off1[b * 4 + t] = p; p += hist1[b * 4 + t]; }
    } else if (t < 8) {
        int tt = t - 4;
        int p = meta[13 + tt];
        for (int b = 0; b < NB; b++) { off2[b * 4 + tt] = p; p += hist2[b * 4 + tt]; }
    }
}

// ---------------- pass 3: write edge ids at exact offsets (LDS atomics only) ----------------
__global__ __launch_bounds__(256) void write_sorted(const int* __restrict__ type,
                                                    int n,
                                                    const int* __restrict__ off,
                                                    int* __restrict__ sorted) {
    __shared__ int loff[4];
    if (threadIdx.x < 4) loff[threadIdx.x] = off[blockIdx.x * 4 + threadIdx.x];
    __syncthreads();
    for (int i = blockIdx.x * 256 + threadIdx.x; i < n; i += NB * 256) {
        int t = type[i];
        int pos = atomicAdd(&loff[t], 1);
        sorted[pos] = i;
    }
}

// ================= MFMA edge kernels =================
// Block = 32 edges (one type), 4 waves. Wave w computes out cols [32w, 32w+32).
// A (32 x K) staged bf16 in LDS with XOR swizzle; B frags read from Wt (L2).
// mfma_f32_16x16x32_bf16 C/D: col=lane&15, row=(lane>>4)*4+reg  [guide m89]

__global__ __launch_bounds__(256) void edge1_mfma(
    const float* __restrict__ x, const unsigned short* __restrict__ Wt1,
    const int* __restrict__ src, const int* __restrict__ tgt,
    const int* __restrict__ sorted, const int* __restrict__ meta,
    float* __restrict__ out) {
    __shared__ uint4 As4[512];  // 32 rows x 256B (swizzled)
    __shared__ int s_tgt[EPB];
    __shared__ int s_src[EPB];
    char* As = (char*)As4;

    int tid = threadIdx.x;
    int g0 = blockIdx.x * EPB;
    const int* pb = meta + 8;
    int t = 0;
#pragma unroll
    for (int k = 1; k < 4; k++)
        if (g0 >= pb[k]) t = k;
    const unsigned short* __restrict__ W = Wt1 + (size_t)t * D * D;

    if (tid < EPB) {
        int eid = sorted[g0 + tid];
        int sv = -1, tv = -1;
        if (eid >= 0) { sv = src[eid]; tv = tgt[eid]; }
        s_src[tid] = sv;
        s_tgt[tid] = tv;
    }
    __syncthreads();

    {
        int r = tid >> 3, u0 = tid & 7;
        int sv = s_src[r];
        const float4* srow = (const float4*)(x + (size_t)sv * D);
#pragma unroll
        for (int q = 0; q < 4; q++) {
            int u = u0 + 8 * q;  // float4 unit 0..31
            float4 v = make_float4(0.f, 0.f, 0.f, 0.f);
            if (sv >= 0) v = srow[u];
            uint2 p;
            p.x = (unsigned)f2bf(v.x) | ((unsigned)f2bf(v.y) << 16);
            p.y = (unsigned)f2bf(v.z) | ((unsigned)f2bf(v.w) << 16);
            int byte = ((((u >> 1) * 16) ^ ((r & 7) << 4)) + (u & 1) * 8);
            *(uint2*)(As + r * 256 + byte) = p;
        }
    }
    __syncthreads();

    int wave = tid >> 6, lane = tid & 63;
    int c0 = wave * 32;
    int lrow = lane & 15, lgrp = lane >> 4;

    bf16x8 b[2][4];
#pragma unroll
    for (int fc = 0; fc < 2; fc++)
#pragma unroll
        for (int kk = 0; kk < 4; kk++)
            b[fc][kk] = *(const bf16x8*)(W + (size_t)(c0 + fc * 16 + lrow) * D +
                                         kk * 32 + lgrp * 8);

    f32x4 acc[2][2];
#pragma unroll
    for (int i = 0; i < 2; i++)
#pragma unroll
        for (int j = 0; j < 2; j++) acc[i][j] = (f32x4){0.f, 0.f, 0.f, 0.f};

#pragma unroll
    for (int kk = 0; kk < 4; kk++) {
        bf16x8 a0, a1;
        {
            int r = lrow;
            a0 = *(const bf16x8*)(As + r * 256 +
                                  ((kk * 64 + lgrp * 16) ^ ((r & 7) << 4)));
        }
        {
            int r = 16 + lrow;
            a1 = *(const bf16x8*)(As + r * 256 +
                                  ((kk * 64 + lgrp * 16) ^ ((r & 7) << 4)));
        }
        acc[0][0] = __builtin_amdgcn_mfma_f32_16x16x32_bf16(a0, b[0][kk], acc[0][0], 0, 0, 0);
        acc[1][0] = __builtin_amdgcn_mfma_f32_16x16x32_bf16(a1, b[0][kk], acc[1][0], 0, 0, 0);
        acc[0][1] = __builtin_amdgcn_mfma_f32_16x16x32_bf16(a0, b[1][kk], acc[0][1], 0, 0, 0);
        acc[1][1] = __builtin_amdgcn_mfma_f32_16x16x32_bf16(a1, b[1][kk], acc[1][1], 0, 0, 0);
    }

#pragma unroll
    for (int fr = 0; fr < 2; fr++)
#pragma unroll
        for (int reg = 0; reg < 4; reg++) {
            int erow = fr * 16 + lgrp * 4 + reg;
            int tv = s_tgt[erow];
            if (tv >= 0) {
#pragma unroll
                for (int fc = 0; fc < 2; fc++)
                    atomicAdd(&out[(size_t)tv * D + c0 + fc * 16 + lrow],
                              acc[fr][fc][reg]);
            }
        }
}

__global__ __launch_bounds__(256) void edge2_mfma(
    const float* __restrict__ x, const unsigned short* __restrict__ Wt2,
    const int* __restrict__ src2, const int* __restrict__ tgt,
    const int* __restrict__ sorted, const int* __restrict__ meta,
    float* __restrict__ out) {
    __shared__ uint4 As4[1024];  // 32 rows x 512B (swizzled)
    __shared__ int s_tgt[EPB];
    __shared__ int s_srcA[EPB];
    __shared__ int s_srcB[EPB];
    char* As = (char*)As4;

    int tid = threadIdx.x;
    int g0 = blockIdx.x * EPB;
    const int* pb = meta + 13;
    int t = 0;
#pragma unroll
    for (int k = 1; k < 4; k++)
        if (g0 >= pb[k]) t = k;
    const unsigned short* __restrict__ W = Wt2 + (size_t)t * D * 2 * D;

    if (tid < EPB) {
        int eid = sorted[g0 + tid];
        int sa = -1, sb = -1, tv = -1;
        if (eid >= 0) { sa = src2[2 * eid]; sb = src2[2 * eid + 1]; tv = tgt[eid]; }
        s_srcA[tid] = sa;
        s_srcB[tid] = sb;
        s_tgt[tid] = tv;
    }
    __syncthreads();

    {
        int r = tid >> 3, u0 = tid & 7;
        int sa = s_srcA[r], sb = s_srcB[r];
        const float4* rowA = (const float4*)(x + (size_t)sa * D);
        const float4* rowB = (const float4*)(x + (size_t)sb * D);
#pragma unroll
        for (int q = 0; q < 8; q++) {
            int u = u0 + 8 * q;  // float4 unit 0..63 over concat row
            float4 v = make_float4(0.f, 0.f, 0.f, 0.f);
            if (sa >= 0) v = (u < 32) ? rowA[u] : rowB[u - 32];
            uint2 p;
            p.x = (unsigned)f2bf(v.x) | ((unsigned)f2bf(v.y) << 16);
            p.y = (unsigned)f2bf(v.z) | ((unsigned)f2bf(v.w) << 16);
            int byte = ((((u >> 1) * 16) ^ ((r & 7) << 4)) + (u & 1) * 8);
            *(uint2*)(As + r * 512 + byte) = p;
        }
    }
    __syncthreads();

    int wave = tid >> 6, lane = tid & 63;
    int c0 = wave * 32;
    int lrow = lane & 15, lgrp = lane >> 4;

    f32x4 acc[2][2];
#pragma unroll
    for (int i = 0; i < 2; i++)
#pragma unroll
        for (int j = 0; j < 2; j++) acc[i][j] = (f32x4){0.f, 0.f, 0.f, 0.f};

#pragma unroll
    for (int kk = 0; kk < 8; kk++) {
        bf16x8 b0 = *(const bf16x8*)(W + (size_t)(c0 + lrow) * 2 * D + kk * 32 + lgrp * 8);
        bf16x8 b1 = *(const bf16x8*)(W + (size_t)(c0 + 16 + lrow) * 2 * D + kk * 32 + lgrp * 8);
        bf16x8 a0, a1;
        {
            int r = lrow;
            a0 = *(const bf16x8*)(As + r * 512 +
                                  ((kk * 64 + lgrp * 16) ^ ((r & 7) << 4)));
        }
        {
            int r = 16 + lrow;
            a1 = *(const bf16x8*)(As + r * 512 +
                                  ((kk * 64 + lgrp * 16) ^ ((r & 7) << 4)));
        }
        acc[0][0] = __builtin_amdgcn_mfma_f32_16x16x32_bf16(a0, b0, acc[0][0], 0, 0, 0);
        acc[1][0] = __builtin_amdgcn_mfma_f32_16x16x32_bf16(a1, b0, acc[1][0], 0, 0, 0);
        acc[0][1] = __builtin_amdgcn_mfma_f32_16x16x32_bf16(a0, b1, acc[0][1], 0, 0, 0);
        acc[1][1] = __builtin_amdgcn_mfma_f32_16x16x32_bf16(a1, b1, acc[1][1], 0, 0, 0);
    }

#pragma unroll
    for (int fr = 0; fr < 2; fr++)
#pragma unroll
        for (int reg = 0; reg < 4; reg++) {
            int erow = fr * 16 + lgrp * 4 + reg;
            int tv = s_tgt[erow];
            if (tv >= 0) {
#pragma unroll
                for (int fc = 0; fc < 2; fc++)
                    atomicAdd(&out[(size_t)tv * D + c0 + fc * 16 + lrow],
                              acc[fr][fc][reg]);
            }
        }
}

// ---------------- fallback (no workspace): one wave per edge, fp32 ----------------
__global__ __launch_bounds__(256) void e1_simple(
    const float* __restrict__ x, const float* __restrict__ W1,
    const int* __restrict__ src, const int* __restrict__ tgt,
    const int* __restrict__ type, float* __restrict__ out, int n) {
    int lane = threadIdx.x & 63;
    int wid = (blockIdx.x * blockDim.x + threadIdx.x) >> 6;
    int nw = (gridDim.x * blockDim.x) >> 6;
    for (int e = wid; e < n; e += nw) {
        const float* W = W1 + (size_t)type[e] * D * D;
        const float* xr = x + (size_t)src[e] * D;
        float a0 = 0.f, a1 = 0.f;
        for (int i = 0; i < D; i++) {
            float xv = xr[i];
            a0 = fmaf(xv, W[i * D + lane], a0);
            a1 = fmaf(xv, W[i * D + 64 + lane], a1);
        }
        atomicAdd(&out[(size_t)tgt[e] * D + lane], a0);
        atomicAdd(&out[(size_t)tgt[e] * D + 64 + lane], a1);
    }
}

__global__ __launch_bounds__(256) void e2_simple(
    const float* __restrict__ x, const float* __restrict__ W2,
    const int* __restrict__ src2, const int* __restrict__ tgt,
    const int* __restrict__ type, float* __restrict__ out, int n) {
    int lane = threadIdx.x & 63;
    int wid = (blockIdx.x * blockDim.x + threadIdx.x) >> 6;
    int nw = (gridDim.x * blockDim.x) >> 6;
    for (int e = wid; e < n; e += nw) {
        const float* W = W2 + (size_t)type[e] * 2 * D * D;
        const float* xrA = x + (size_t)src2[2 * e] * D;
        const float* xrB = x + (size_t)src2[2 * e + 1] * D;
        float a0 = 0.f, a1 = 0.f;
        for (int i = 0; i < 2 * D; i++) {
            float xv = (i < D) ? xrA[i] : xrB[i - D];
            a0 = fmaf(xv, W[i * D + lane], a0);
            a1 = fmaf(xv, W[i * D + 64 + lane], a1);
        }
        atomicAdd(&out[(size_t)tgt[e] * D + lane], a0);
        atomicAdd(&out[(size_t)tgt[e] * D + 64 + lane], a1);
    }
}

extern "C" void kernel_launch(void* const* d_in, const int* in_sizes, int n_in,
                              void* d_out, int out_size, void* d_ws, size_t ws_size,
                              hipStream_t stream) {
    const float* x = (const float*)d_in[0];
    const float* W1 = (const float*)d_in[1];
    const float* W2 = (const float*)d_in[2];
    const int* src1 = (const int*)d_in[3];
    const int* tgt1 = (const int*)d_in[4];
    const int* type1 = (const int*)d_in[5];
    const int* src2 = (const int*)d_in[6];
    const int* tgt2 = (const int*)d_in[7];
    const int* type2 = (const int*)d_in[8];
    float* out = (float*)d_out;

    int n_nodes = in_sizes[0] / D;
    int E1c = in_sizes[3];
    int E2c = in_sizes[7];

    copy_kernel<<<2048, 256, 0, stream>>>(out, x, n_nodes * D);

    int grid1 = (E1c + 4 * (EPB - 1) + EPB - 1) / EPB;
    int grid2 = (E2c + 4 * (EPB - 1) + EPB - 1) / EPB;
    int cap1 = grid1 * EPB;
    int cap2 = grid2 * EPB;

    // ws layout: meta(32 ints) | hist1 | off1 | hist2 | off2 | sorted1 | sorted2 | wt1 | wt2
    size_t ints_head = 32 + (size_t)4 * NB * 4;
    size_t base = ints_head * 4 + (size_t)4 * (cap1 + cap2);
    base = (base + 255) & ~(size_t)255;
    size_t w1_elems = (size_t)4 * D * D;       // 65536
    size_t w2_elems = (size_t)4 * D * 2 * D;   // 131072
    size_t need = base + (w1_elems + w2_elems) * 2;

    if (ws_size >= need) {
        int* meta = (int*)d_ws;
        int* hist1 = meta + 32;
        int* off1 = hist1 + NB * 4;
        int* hist2 = off1 + NB * 4;
        int* off2 = hist2 + NB * 4;
        int* sorted1 = off2 + NB * 4;
        int* sorted2 = sorted1 + cap1;
        unsigned short* wt1 = (unsigned short*)((char*)d_ws + base);
        unsigned short* wt2 = wt1 + w1_elems;

        hipMemsetAsync(sorted1, 0xFF, (size_t)4 * (cap1 + cap2), stream);

        conv_w<<<dim3(4, 4, 4), 256, 0, stream>>>(W1, wt1, D);
        conv_w<<<dim3(8, 4, 4), 256, 0, stream>>>(W2, wt2, 2 * D);

        hist_types<<<NB, 256, 0, stream>>>(type1, E1c, hist1);
        hist_types<<<NB, 256, 0, stream>>>(type2, E2c, hist2);
        scan_offsets<<<1, 64, 0, stream>>>(meta, hist1, off1, hist2, off2);
        write_sorted<<<NB, 256, 0, stream>>>(type1, E1c, off1, sorted1);
        write_sorted<<<NB, 256, 0, stream>>>(type2, E2c, off2, sorted2);

        edge1_mfma<<<grid1, 256, 0, stream>>>(x, wt1, src1, tgt1, sorted1, meta, out);
        edge2_mfma<<<grid2, 256, 0, stream>>>(x, wt2, src2, tgt2, sorted2, meta, out);
    } else {
        e1_simple<<<2048, 256, 0, stream>>>(x, W1, src1, tgt1, type1, out, E1c);
        e2_simple<<<2048, 256, 0, stream>>>(x, W2, src2, tgt2, type2, out, E2c);
    }
}